// Round 13
// baseline (105.038 us; speedup 1.0000x reference)
//
#include <hip/hip_runtime.h>
#include <stdint.h>

#define B_ 64
#define T_ 4096
#define H_ 256
#define U_ 256

typedef float f32x4 __attribute__((ext_vector_type(4)));
typedef short short8 __attribute__((ext_vector_type(8)));
typedef unsigned int uint2v __attribute__((ext_vector_type(2)));

__device__ __forceinline__ short bf16rne(float f) {
    uint32_t x = __builtin_bit_cast(uint32_t, f);
    return (short)((x + 0x7FFFu + ((x >> 16) & 1u)) >> 16);
}

__device__ __forceinline__ float fast_tanh(float x) {
    float e = __expf(2.0f * x);
    return 1.0f - 2.0f * __builtin_amdgcn_rcpf(e + 1.0f);
}

// Barrier that orders LDS only (lgkmcnt); global loads stay in flight (R6-proven correct).
__device__ __forceinline__ void wg_barrier_lds() {
    asm volatile("s_waitcnt lgkmcnt(0)" ::: "memory");
    __builtin_amdgcn_sched_barrier(0);
    __builtin_amdgcn_s_barrier();
    __builtin_amdgcn_sched_barrier(0);
}

// pack 4 fp32 -> 4 bf16 (RNE) in 2 dwords (R12-verified numerically identical to bf16rne)
__device__ __forceinline__ uint2v pack_bf16x4(const f32x4 a) {
    uint32_t w0, w1;
    asm("v_cvt_pk_bf16_f32 %0, %1, %2" : "=v"(w0) : "v"(a[0]), "v"(a[1]));
    asm("v_cvt_pk_bf16_f32 %0, %1, %2" : "=v"(w1) : "v"(a[2]), "v"(a[3]));
    uint2v r; r[0] = w0; r[1] = w1;
    return r;
}

// ---- fused prep: blocks 0-255 convert W2 -> w2t[u][h] bf16; blocks 256-319 qproj ----
__global__ __launch_bounds__(256) void k_prep(const float* __restrict__ W2,
                                              uint16_t* __restrict__ w2t,
                                              const float* __restrict__ query,
                                              const float* __restrict__ W1,
                                              const float* __restrict__ b1,
                                              const float* __restrict__ b2,
                                              float* __restrict__ qpc) {
    if (blockIdx.x < 256) {
        int idx = blockIdx.x * 256 + threadIdx.x;
        int h = idx >> 8;
        int u = idx & 255;
        w2t[u * 256 + h] = (uint16_t)bf16rne(W2[idx]);
    } else {
        __shared__ float qrow[H_];
        int b = blockIdx.x - 256, u = threadIdx.x;
        qrow[u] = query[b * H_ + u];
        __syncthreads();
        float acc = b1[u] + b2[u];
#pragma unroll 8
        for (int h = 0; h < H_; ++h) acc += qrow[h] * W1[h * U_ + u];
        qpc[b * U_ + u] = acc;
    }
}

// ---------------- fused main: R11 schedule + fully-contiguous load instructions --------
// vs R11 (92.65us): ONLY the memory-op lane mapping changed.  Load instruction k of
// wave wv covers tile row wv*4+k contiguously (lane p -> bytes p*16 of the 1KB fp32
// row) -> every global dwordx4 is full-line (R11: 32B-stride lanes = half-line).
// Per-thread cols fixed (4 floats): Oacc 16->4 regs, Ored 32KB->8KB; exp by 4 lanes +
// shfl broadcast.  MFMA phase / swizzle / red / 2-barrier loop: identical to R11.
#define TR 32
#define NT 8
__global__ __launch_bounds__(512, 2) void k_main(const float* __restrict__ values,
                                                 const uint16_t* __restrict__ w2t,
                                                 const float* __restrict__ qpc,
                                                 const float* __restrict__ V,
                                                 float* __restrict__ score,
                                                 float* __restrict__ part_O,
                                                 float* __restrict__ part_s) {
    __shared__ __align__(16) char Ab[TR * 512];   // bf16 [32][256], byte ^= ((row&7)<<4)
    __shared__ __align__(16) float red[TR][12];   // [row][wave0..7], 48B rows
    __shared__ __align__(16) float Ored[8][260];  // per-wave ctx partials (8 KB)
    __shared__ float sred[8];

    const int tid = threadIdx.x;
    const int wg = blockIdx.x;          // 0..1023
    const int b = wg >> 4;
    const int chunk = (wg & 15) * (NT * TR);

    const int wv = tid >> 6;            // wave 0..7
    const int p = tid & 63;             // lane
    const int c = p & 15;
    const int g = p >> 4;

    // A fragments (W2) in regs: 2 strips x 8 ks (64 VGPR) — unchanged
    short8 afr[2][8];
#pragma unroll
    for (int s = 0; s < 2; ++s) {
        const uint16_t* ap = w2t + (size_t)(wv * 32 + s * 16 + c) * 256 + g * 8;
#pragma unroll
        for (int ks = 0; ks < 8; ++ks) afr[s][ks] = *(const short8*)(ap + ks * 32);
    }
    float qv[2][4], vv[2][4];
#pragma unroll
    for (int s = 0; s < 2; ++s)
#pragma unroll
        for (int r = 0; r < 4; ++r) {
            int u = wv * 32 + s * 16 + g * 4 + r;
            qv[s][r] = qpc[b * U_ + u];
            vv[s][r] = V[u];
        }

    const float* vbase = values + (size_t)b * T_ * H_;
    const int r0 = wv * 4;              // this wave's 4 memory rows (per tile)
    // LDS stage destinations (row-uniform per instruction, 4-way uniform banks)
    char* st0 = Ab + (r0 + 0) * 512 + ((p * 8) ^ (((r0 + 0) & 7) << 4));
    char* st1 = Ab + (r0 + 1) * 512 + ((p * 8) ^ (((r0 + 1) & 7) << 4));
    char* st2 = Ab + (r0 + 2) * 512 + ((p * 8) ^ (((r0 + 2) & 7) << 4));
    char* st3 = Ab + (r0 + 3) * 512 + ((p * 8) ^ (((r0 + 3) & 7) << 4));
    const float* lb = vbase + (size_t)r0 * H_ + p * 4;   // + (chunk + t*TR)*H_ (+k*H_)

    f32x4 vt0, vt1, vt2, vt3;           // rows r0..r0+3 of one tile (time-shared slot)
    float Oacc[4] = {0.f, 0.f, 0.f, 0.f};
    float sacc = 0.f;

    {   // prologue: load tile 0 (each instruction = one contiguous 1KB row)
        const float* nb = lb + (size_t)chunk * H_;
        vt0 = *(const f32x4*)(nb);
        vt1 = *(const f32x4*)(nb + H_);
        vt2 = *(const f32x4*)(nb + 2 * H_);
        vt3 = *(const f32x4*)(nb + 3 * H_);
    }

#pragma unroll
    for (int t = 0; t < NT; ++t) {
        wg_barrier_lds();               // B1: red(t-1) ready; Ab readers done
        // ---- stage tile t (from vt) -> bf16 swizzled LDS, 4x ds_write_b64 ----
        *(uint2v*)st0 = pack_bf16x4(vt0);
        *(uint2v*)st1 = pack_bf16x4(vt1);
        *(uint2v*)st2 = pack_bf16x4(vt2);
        *(uint2v*)st3 = pack_bf16x4(vt3);
        // ---- consume tile t-1: L2 re-read (contiguous rows) + weights + ctx accum ----
        if (t > 0) {
            const float* rb = lb + (size_t)(chunk + (t - 1) * TR) * H_;
            vt0 = *(const f32x4*)(rb);
            vt1 = *(const f32x4*)(rb + H_);
            vt2 = *(const f32x4*)(rb + 2 * H_);
            vt3 = *(const f32x4*)(rb + 3 * H_);
            float pexp = 0.f;
            if (p < 4) {
                const float* rr = &red[r0 + p][0];
                f32x4 s0 = *(const f32x4*)(rr);
                f32x4 s1 = *(const f32x4*)(rr + 4);
                float ssum = ((s0[0] + s0[1]) + (s0[2] + s0[3])) +
                             ((s1[0] + s1[1]) + (s1[2] + s1[3]));
                pexp = __expf(ssum);
                sacc += pexp;
                score[(size_t)b * T_ + chunk + (t - 1) * TR + r0 + p] = ssum;
            }
            float w0 = __shfl(pexp, 0, 64);
            float w1 = __shfl(pexp, 1, 64);
            float w2 = __shfl(pexp, 2, 64);
            float w3 = __shfl(pexp, 3, 64);
#pragma unroll
            for (int j = 0; j < 4; ++j)
                Oacc[j] += w0 * vt0[j] + w1 * vt1[j] + w2 * vt2[j] + w3 * vt3[j];
        }
        // ---- prefetch tile t+1 (HBM, contiguous rows) into vt ----
        if (t + 1 < NT) {
            const float* nb = lb + (size_t)(chunk + (t + 1) * TR) * H_;
            vt0 = *(const f32x4*)(nb);
            vt1 = *(const f32x4*)(nb + H_);
            vt2 = *(const f32x4*)(nb + 2 * H_);
            vt3 = *(const f32x4*)(nb + 3 * H_);
        }
        wg_barrier_lds();               // B2: Ab(t) staged
        // ---- MFMA phase on tile t (identical to R11) ----
#pragma unroll
        for (int sub = 0; sub < 2; ++sub) {
            const char* rp = Ab + (sub * 16 + c) * 512;
            const int swz = (c & 7) << 4;
            f32x4 acc0 = (f32x4)(0.0f);
            f32x4 acc1 = (f32x4)(0.0f);
#pragma unroll
            for (int ks = 0; ks < 8; ++ks) {
                short8 bf = *(const short8*)(rp + ((ks * 64 + g * 16) ^ swz));
                acc0 = __builtin_amdgcn_mfma_f32_16x16x32_bf16(afr[0][ks], bf, acc0, 0, 0, 0);
                acc1 = __builtin_amdgcn_mfma_f32_16x16x32_bf16(afr[1][ks], bf, acc1, 0, 0, 0);
            }
            float ps = 0.f;
#pragma unroll
            for (int r = 0; r < 4; ++r) {
                ps += fast_tanh(acc0[r] + qv[0][r]) * vv[0][r];
                ps += fast_tanh(acc1[r] + qv[1][r]) * vv[1][r];
            }
            ps += __shfl_xor(ps, 16, 64);
            ps += __shfl_xor(ps, 32, 64);
            if (g == 0) red[sub * 16 + c][wv] = ps;
        }
    }
    __syncthreads();
    {   // final consume: tile NT-1 (re-read from L2)
        const float* rb = lb + (size_t)(chunk + (NT - 1) * TR) * H_;
        vt0 = *(const f32x4*)(rb);
        vt1 = *(const f32x4*)(rb + H_);
        vt2 = *(const f32x4*)(rb + 2 * H_);
        vt3 = *(const f32x4*)(rb + 3 * H_);
        float pexp = 0.f;
        if (p < 4) {
            const float* rr = &red[r0 + p][0];
            f32x4 s0 = *(const f32x4*)(rr);
            f32x4 s1 = *(const f32x4*)(rr + 4);
            float ssum = ((s0[0] + s0[1]) + (s0[2] + s0[3])) +
                         ((s1[0] + s1[1]) + (s1[2] + s1[3]));
            pexp = __expf(ssum);
            sacc += pexp;
            score[(size_t)b * T_ + chunk + (NT - 1) * TR + r0 + p] = ssum;
        }
        float w0 = __shfl(pexp, 0, 64);
        float w1 = __shfl(pexp, 1, 64);
        float w2 = __shfl(pexp, 2, 64);
        float w3 = __shfl(pexp, 3, 64);
#pragma unroll
        for (int j = 0; j < 4; ++j)
            Oacc[j] += w0 * vt0[j] + w1 * vt1[j] + w2 * vt2[j] + w3 * vt3[j];
    }
    // epilogue: per-wave ctx rows, then cross-wave reduce
    *(f32x4*)(&Ored[wv][p * 4]) = *(f32x4*)Oacc;
    sacc += __shfl_xor(sacc, 1, 64);
    sacc += __shfl_xor(sacc, 2, 64);
    if (p == 0) sred[wv] = sacc;
    __syncthreads();
    if (tid < 256) {
        float o = 0.f;
#pragma unroll
        for (int j = 0; j < 8; ++j) o += Ored[j][tid];
        part_O[(size_t)wg * 256 + tid] = o;
    }
    if (tid == 0) {
        float sb = 0.f;
#pragma unroll
        for (int j = 0; j < 8; ++j) sb += sred[j];
        part_s[wg] = sb;
    }
}

// ---------------- finish: reduce partials, write ctx + normalized weights ----------------
__global__ __launch_bounds__(256) void k_fin(const float* __restrict__ part_O,
                                             const float* __restrict__ part_s,
                                             const float* __restrict__ score,
                                             float* __restrict__ ctx,
                                             float* __restrict__ weights) {
    int b = blockIdx.x >> 3;
    int j = blockIdx.x & 7;
    int col = threadIdx.x;
    float sb = 0.f;
#pragma unroll
    for (int ch = 0; ch < 16; ++ch) sb += part_s[b * 16 + ch];
    float inv = 1.0f / sb;
    if (j == 0) {
        float o = 0.f;
#pragma unroll
        for (int ch = 0; ch < 16; ++ch) o += part_O[(size_t)(b * 16 + ch) * 256 + col];
        ctx[b * H_ + col] = o * inv;
    }
#pragma unroll
    for (int i = 0; i < 2; ++i) {
        int idx = j * 512 + i * 256 + col;
        float s = score[(size_t)b * T_ + idx];
        weights[(size_t)b * T_ + idx] = __expf(s) * inv;
    }
}

extern "C" void kernel_launch(void* const* d_in, const int* in_sizes, int n_in,
                              void* d_out, int out_size, void* d_ws, size_t ws_size,
                              hipStream_t stream) {
    const float* query  = (const float*)d_in[0];
    const float* values = (const float*)d_in[1];
    const float* W1     = (const float*)d_in[2];
    const float* b1     = (const float*)d_in[3];
    const float* W2     = (const float*)d_in[4];
    const float* b2     = (const float*)d_in[5];
    const float* V      = (const float*)d_in[6];
    // d_in[7] = bV: softmax is shift-invariant -> no effect on outputs.

    float* out = (float*)d_out;
    float* ctx = out;                    // [B,H]
    float* weights = out + B_ * H_;      // [B,T,1]

    char* ws = (char*)d_ws;
    uint16_t* w2t   = (uint16_t*)ws;                               // 128 KB
    float* qpc      = (float*)(ws + 131072);                       // 64 KB
    float* scorebuf = (float*)(ws + 131072 + 65536);               // 1 MB
    float* part_O   = (float*)(ws + 131072 + 65536 + 1048576);     // 1 MB
    float* part_s   = (float*)(ws + 131072 + 65536 + 2097152);     // 4 KB

    k_prep<<<dim3(320), dim3(256), 0, stream>>>(W2, w2t, query, W1, b1, b2, qpc);
    k_main<<<dim3(1024), dim3(512), 0, stream>>>(values, w2t, qpc, V, scorebuf,
                                                 part_O, part_s);
    k_fin<<<dim3(512), dim3(256), 0, stream>>>(part_O, part_s, scorebuf, ctx, weights);
}